// Round 11
// baseline (1078.534 us; speedup 1.0000x reference)
//
#include <hip/hip_runtime.h>
#include <math.h>

typedef float f4 __attribute__((ext_vector_type(4)));
typedef float f32x4 __attribute__((ext_vector_type(4)));
typedef _Float16 f16;
typedef _Float16 f16x8 __attribute__((ext_vector_type(8)));

#define NB 16384
#define BERT_DIM 768
#define CONDD 64
#define INUMD 10
#define RNND 128
#define TDIFFN 200
#define SAMPLE_TN 50
#define TEMBD 64
#define TMAXN 64

struct Sched { float c1[SAMPLE_TN], c2[SAMPLE_TN], sv[SAMPLE_TN], ts[SAMPLE_TN]; };

__device__ __forceinline__ float fsig(float v)  { return __builtin_amdgcn_rcpf(1.f + __expf(-v)); }
__device__ __forceinline__ float ftanh(float v) { return 1.f - 2.f * __builtin_amdgcn_rcpf(1.f + __expf(2.f * v)); }
__device__ __forceinline__ float fsilu(float v) { return v * fsig(v); }

// ---------------- pack: transposed / fp16 weights ----------------
__global__ __launch_bounds__(256) void pack_kernel(
    const float* __restrict__ dn_w1, const float* __restrict__ dn_w2,
    const float* __restrict__ dn_w3, const float* __restrict__ gru_wh,
    const float* __restrict__ h0_w, const float* __restrict__ bp_w,
    float* __restrict__ w1ct, f16* __restrict__ w1x16, f16* __restrict__ w2f16,
    f16* __restrict__ whf16, float* __restrict__ h0wp, f16* __restrict__ bpw16,
    f16* __restrict__ w3f16)
{
    int idx = blockIdx.x * 256 + threadIdx.x;   // 0..65535
    if (idx < 16384) { int k = idx >> 8, n = idx & 255; w1ct[idx] = dn_w1[n * 138 + 10 + k]; }
    if (idx < 8192)  { int n = idx >> 5, k = idx & 31; w1x16[idx] = (f16)(k < 10 ? dn_w1[n * 138 + k] : 0.f); }
    if (idx < 65536) { w2f16[idx] = (f16)dn_w2[idx]; }                 // [n=256][k=256]
    if (idx < 49152) { whf16[idx] = (f16)gru_wh[idx]; }                // [n=384][k=128]
    if (idx < 9728)  { int r = idx / 76, c = idx % 76; h0wp[idx] = (c < 74) ? h0_w[r * 74 + c] : 0.f; }
    if (idx < 49152) { bpw16[idx] = (f16)bp_w[idx]; }                  // [n=64][k=768]
    if (idx < 4096)  { int n = idx >> 8, k = idx & 255; w3f16[idx] = (f16)(n < 10 ? dn_w3[n * 256 + k] : 0.f); }
}

// ---------------- bert proj + LN, fp16 MFMA: 64 rows/block, W staged in LDS ----------------
__global__ __launch_bounds__(256, 1) void bert2_kernel(
    const float* __restrict__ bert, const f16* __restrict__ bpw16,
    const float* __restrict__ bp_b, const float* __restrict__ ln_g,
    const float* __restrict__ ln_b, float* __restrict__ cond)
{
    __shared__ __align__(16) f16 ws16[64 * 768];   // 96 KB, swizzled: n*1536B + (k*2 ^ ((n&7)<<4))
    int tid = threadIdx.x;
    int row0 = blockIdx.x * 64;
    int lane = tid & 63, wn = tid >> 6;
    int l15 = lane & 15, l4 = lane >> 4;

    // stage W (f16x8 granules; XOR bits 4-6 keep 16B alignment)
    for (int u = tid; u < 6144; u += 256) {
        int n = u / 96, k8 = u % 96;
        *(f16x8*)((char*)ws16 + n * 1536 + ((k8 * 16) ^ ((n & 7) << 4))) =
            *(const f16x8*)(bpw16 + n * 768 + k8 * 8);
    }
    __syncthreads();

    const float* aptr = bert + (size_t)(row0 + wn * 16 + l15) * BERT_DIM;
    f32x4 acc[4];
    #pragma unroll
    for (int t = 0; t < 4; ++t) {
        float bb = bp_b[t * 16 + l15];
        acc[t][0] = bb; acc[t][1] = bb; acc[t][2] = bb; acc[t][3] = bb;
    }
    #pragma unroll 4
    for (int kb = 0; kb < 24; ++kb) {
        f4 a0 = *(const f4*)(aptr + kb * 32 + l4 * 8);
        f4 a1 = *(const f4*)(aptr + kb * 32 + l4 * 8 + 4);
        f16x8 af;
        #pragma unroll
        for (int j = 0; j < 4; ++j) { af[j] = (f16)a0[j]; af[4 + j] = (f16)a1[j]; }
        #pragma unroll
        for (int t = 0; t < 4; ++t) {
            int col = t * 16 + l15;
            f16x8 bf = *(const f16x8*)((const char*)ws16 +
                        (col * 1536 + ((kb * 64 + l4 * 16) ^ ((col & 7) << 4))));
            acc[t] = __builtin_amdgcn_mfma_f32_16x16x32_f16(af, bf, acc[t], 0, 0, 0);
        }
    }
    // LN over 64 cols; D-layout: row = l4*4+r, col = t*16+l15
    float s[4] = {0,0,0,0}, s2[4] = {0,0,0,0};
    #pragma unroll
    for (int r = 0; r < 4; ++r)
        #pragma unroll
        for (int t = 0; t < 4; ++t) { float v = acc[t][r]; s[r] += v; s2[r] += v * v; }
    #pragma unroll
    for (int r = 0; r < 4; ++r) {
        #pragma unroll
        for (int off = 1; off < 16; off <<= 1) {
            s[r] += __shfl_xor(s[r], off);
            s2[r] += __shfl_xor(s2[r], off);
        }
    }
    float mu[4], inv[4];
    #pragma unroll
    for (int r = 0; r < 4; ++r) {
        mu[r] = s[r] * (1.f / 64.f);
        float var = s2[r] * (1.f / 64.f) - mu[r] * mu[r];
        inv[r] = rsqrtf(var + 1e-5f);
    }
    #pragma unroll
    for (int t = 0; t < 4; ++t) {
        int col = t * 16 + l15;
        float g = ln_g[col], b = ln_b[col];
        #pragma unroll
        for (int r = 0; r < 4; ++r) {
            int row = row0 + wn * 16 + l4 * 4 + r;
            cond[(size_t)row * CONDD + col] = (acc[t][r] - mu[r]) * inv[r] * g + b;
        }
    }
}

// ---------------- time embedding MLP ----------------
__global__ __launch_bounds__(128) void te_kernel(
    const float* __restrict__ tp_w1, const float* __restrict__ tp_b1,
    const float* __restrict__ tp_w2, const float* __restrict__ tp_b2,
    float* __restrict__ te, Sched sc)
{
    __shared__ float temb[TEMBD];
    __shared__ float h[TEMBD * 2];
    int s = blockIdx.x, t = threadIdx.x;
    if (t < 32) {
        float freq = expf(-logf(10000.f) * (float)t / 31.f);
        float e = sc.ts[s] * freq;
        temb[t] = sinf(e);
        temb[t + 32] = cosf(e);
    }
    __syncthreads();
    float a = tp_b1[t];
    for (int k = 0; k < TEMBD; ++k) a += temb[k] * tp_w1[t * TEMBD + k];
    h[t] = a * (1.f / (1.f + expf(-a)));
    __syncthreads();
    if (t < TEMBD) {
        float a2 = tp_b2[t];
        for (int k = 0; k < 128; ++k) a2 += h[k] * tp_w2[t * 128 + k];
        te[s * TEMBD + t] = a2;
    }
}

// ---------------- b1eff[s][n] = b1[n] + sum_k te[s][k]*w1[n][74+k] ----------------
__global__ __launch_bounds__(256) void b1eff_kernel(
    const float* __restrict__ te, const float* __restrict__ dn_w1,
    const float* __restrict__ dn_b1, float* __restrict__ b1eff)
{
    __shared__ float tes[64];
    int s = blockIdx.x, n = threadIdx.x;
    if (n < 64) tes[n] = te[s * 64 + n];
    __syncthreads();
    float a = dn_b1[n];
    for (int k = 0; k < 64; ++k) a += tes[k] * dn_w1[n * 138 + 74 + k];
    b1eff[s * 256 + n] = a;
}

// ---------------- DDPM v6: r5 per-wave structure, 32 rows/block (2 m-groups),
// W3 streamed from swizzled LDS (frees 32 regs), grid 512 = exactly 2 blocks/CU ----------------
__global__ __launch_bounds__(256, 2) void ddpm_all_kernel(
    const float* __restrict__ x_init, const float* __restrict__ cond,
    const float* __restrict__ noise,
    const float* __restrict__ w1ct, const f16* __restrict__ w1x16,
    const float* __restrict__ b1eff, const f16* __restrict__ w2f16,
    const float* __restrict__ b2g, const f16* __restrict__ w3f16,
    const float* __restrict__ b3g, Sched sc, float* __restrict__ out_x0)
{
    __shared__ __align__(16) f16 h1[32 * 256];      // 16 KB, swizzled, row stride 512B
    __shared__ __align__(16) f16 h2[32 * 256];      // 16 KB
    __shared__ __align__(16) f16 xw[4][32 * 32];    // per-wave x, linear, row stride 64B
    __shared__ __align__(16) f16 w3s[16 * 256];     // 8 KB, swizzled
    int tid = threadIdx.x;
    int row0 = blockIdx.x * 32;
    int lane = tid & 63, wn = tid >> 6;
    int l15 = lane & 15, l4 = lane >> 4;

    // stage cond fp32 into h1-scratch [32][64]; pack swizzled w3; zero own-wave x buffer
    float* condl = (float*)h1;
    for (int u = tid; u < 32 * 16; u += 256) {
        int r = u >> 4, q = u & 15;
        *(f4*)(condl + r * 64 + q * 4) = *(const f4*)(cond + (size_t)(row0 + r) * 64 + q * 4);
    }
    for (int u = tid; u < 4096; u += 256) {
        int n = u >> 8, k = u & 255;
        *(f16*)((char*)w3s + (n * 512 + ((k * 2) ^ ((n & 7) << 4)))) = w3f16[u];
    }
    *(f4*)((float*)&xw[wn][0] + lane * 4) = (f4)0.f;
    *(f4*)((float*)&xw[wn][0] + 256 + lane * 4) = (f4)0.f;
    __syncthreads();

    // cond1 in regs for both m-groups
    f32x4 c1r[2][4];
    #pragma unroll
    for (int mg = 0; mg < 2; ++mg)
        #pragma unroll
        for (int t = 0; t < 4; ++t) c1r[mg][t] = (f32x4)0.f;
    for (int kq = 0; kq < 16; ++kq) {
        f4 cr0[4], cr1[4];
        #pragma unroll
        for (int r = 0; r < 4; ++r) {
            cr0[r] = *(const f4*)(condl + (l4 * 4 + r) * 64 + kq * 4);
            cr1[r] = *(const f4*)(condl + (16 + l4 * 4 + r) * 64 + kq * 4);
        }
        #pragma unroll
        for (int t = 0; t < 4; ++t) {
            int col = wn * 64 + t * 16 + l15;
            #pragma unroll
            for (int j = 0; j < 4; ++j) {
                float w = w1ct[(kq * 4 + j) * 256 + col];
                #pragma unroll
                for (int r = 0; r < 4; ++r) {
                    c1r[0][t][r] += cr0[r][j] * w;
                    c1r[1][t][r] += cr1[r][j] * w;
                }
            }
        }
    }
    __syncthreads();   // condl scratch done; h1 free for reuse

    // weight-stationary fragments (B2 = 128 VGPR, B1 = 16)
    f16x8 B2[4][8], B1[4];
    float b2v[4];
    #pragma unroll
    for (int t = 0; t < 4; ++t) {
        int col = wn * 64 + t * 16 + l15;
        B1[t] = *(const f16x8*)(w1x16 + col * 32 + l4 * 8);
        #pragma unroll
        for (int kb = 0; kb < 8; ++kb)
            B2[t][kb] = *(const f16x8*)(w2f16 + col * 256 + kb * 32 + l4 * 8);
        b2v[t] = b2g[col];
    }
    float b3v = (l15 < 10) ? b3g[l15] : 0.f;

    // x state: rows mg*16 + l4*4 + r, k = l15
    float xo[2][4] = {{0.f,0.f,0.f,0.f},{0.f,0.f,0.f,0.f}};
    if (l15 < 10) {
        #pragma unroll
        for (int mg = 0; mg < 2; ++mg)
            #pragma unroll
            for (int r = 0; r < 4; ++r) {
                int row = mg * 16 + l4 * 4 + r;
                xo[mg][r] = x_init[(size_t)(row0 + row) * INUMD + l15];
                xw[wn][row * 32 + l15] = (f16)xo[mg][r];
            }
    }
    float be[4];
    #pragma unroll
    for (int t = 0; t < 4; ++t) be[t] = b1eff[wn * 64 + t * 16 + l15];

    #pragma unroll 1
    for (int s = 0; s < SAMPLE_TN; ++s) {
        // ---- L1 (both m-groups): h1 = silu(x @ w1x^T + cond1 + b1eff[s]) ----
        #pragma unroll
        for (int mg = 0; mg < 2; ++mg) {
            f16x8 ax = *(const f16x8*)((const char*)&xw[wn][0] + mg * 1024 + l15 * 64 + l4 * 16);
            #pragma unroll
            for (int t = 0; t < 4; ++t) {
                f32x4 ci;
                #pragma unroll
                for (int r = 0; r < 4; ++r) ci[r] = c1r[mg][t][r] + be[t];
                f32x4 a1 = __builtin_amdgcn_mfma_f32_16x16x32_f16(ax, B1[t], ci, 0, 0, 0);
                int col = wn * 64 + t * 16 + l15;
                #pragma unroll
                for (int r = 0; r < 4; ++r) {
                    int row = mg * 16 + l4 * 4 + r;
                    *(f16*)((char*)h1 + ((row * 512 + col * 2) ^ ((row & 7) << 4))) = (f16)fsilu(a1[r]);
                }
            }
        }
        // prefetch noise (L3) and next-step b1eff
        float nz[2][4] = {{0.f,0.f,0.f,0.f},{0.f,0.f,0.f,0.f}};
        if (l15 < 10) {
            #pragma unroll
            for (int mg = 0; mg < 2; ++mg)
                #pragma unroll
                for (int r = 0; r < 4; ++r)
                    nz[mg][r] = noise[((size_t)s * NB + row0 + mg * 16 + l4 * 4 + r) * INUMD + l15];
        }
        if (s + 1 < SAMPLE_TN) {
            #pragma unroll
            for (int t = 0; t < 4; ++t) be[t] = b1eff[(s + 1) * 256 + wn * 64 + t * 16 + l15];
        }
        __syncthreads();
        // ---- L2 (both m-groups): h2 = silu(h1 @ w2^T + b2) ----
        #pragma unroll
        for (int mg = 0; mg < 2; ++mg) {
            int arow = mg * 16 + l15;
            f32x4 a2[4];
            #pragma unroll
            for (int t = 0; t < 4; ++t) a2[t] = (f32x4)0.f;
            #pragma unroll
            for (int kb = 0; kb < 8; ++kb) {
                f16x8 A = *(const f16x8*)((const char*)h1 +
                          (arow * 512 + ((kb * 64 + l4 * 16) ^ ((arow & 7) << 4))));
                #pragma unroll
                for (int t = 0; t < 4; ++t)
                    a2[t] = __builtin_amdgcn_mfma_f32_16x16x32_f16(A, B2[t][kb], a2[t], 0, 0, 0);
            }
            #pragma unroll
            for (int t = 0; t < 4; ++t) {
                int col = wn * 64 + t * 16 + l15;
                #pragma unroll
                for (int r = 0; r < 4; ++r) {
                    int row = mg * 16 + l4 * 4 + r;
                    *(f16*)((char*)h2 + ((row * 512 + col * 2) ^ ((row & 7) << 4))) = (f16)fsilu(a2[t][r] + b2v[t]);
                }
            }
        }
        __syncthreads();
        // ---- L3 (both m-groups): p = h2 @ w3^T (N=16 padded, W3 from swizzled LDS) ----
        #pragma unroll
        for (int mg = 0; mg < 2; ++mg) {
            int arow = mg * 16 + l15;
            f32x4 pa = (f32x4)0.f, pb = (f32x4)0.f;
            #pragma unroll
            for (int kb = 0; kb < 8; kb += 2) {
                int off0 = ((kb + 0) * 64 + l4 * 16) ^ ((l15 & 7) << 4);
                int off1 = ((kb + 1) * 64 + l4 * 16) ^ ((l15 & 7) << 4);
                f16x8 A0 = *(const f16x8*)((const char*)h2 + (arow * 512 + off0));
                f16x8 W0 = *(const f16x8*)((const char*)w3s + (l15 * 512 + off0));
                f16x8 A1 = *(const f16x8*)((const char*)h2 + (arow * 512 + off1));
                f16x8 W1 = *(const f16x8*)((const char*)w3s + (l15 * 512 + off1));
                pa = __builtin_amdgcn_mfma_f32_16x16x32_f16(A0, W0, pa, 0, 0, 0);
                pb = __builtin_amdgcn_mfma_f32_16x16x32_f16(A1, W1, pb, 0, 0, 0);
            }
            if (l15 < 10) {
                float c1s = sc.c1[s], c2s = sc.c2[s], svs = sc.sv[s];
                #pragma unroll
                for (int r = 0; r < 4; ++r) {
                    int row = mg * 16 + l4 * 4 + r;
                    float xn = c1s * (pa[r] + pb[r] + b3v) + c2s * xo[mg][r] + svs * nz[mg][r];
                    xo[mg][r] = xn;
                    xw[wn][row * 32 + l15] = (f16)xn;
                }
            }
        }
        // no barrier: xw is per-wave; h1 overwrite next iter is post-bar2-safe
    }
    if (wn == 0 && l15 < 10) {
        #pragma unroll
        for (int mg = 0; mg < 2; ++mg)
            #pragma unroll
            for (int r = 0; r < 4; ++r)
                out_x0[(size_t)(row0 + mg * 16 + l4 * 4 + r) * INUMD + l15] = xo[mg][r];
    }
}

// ---------------- GRU v3 (r7/r9/r10-proven): 8 waves x 16 cols, head via dot on A-frags ----------------
__global__ __launch_bounds__(512, 4) void gru_all_kernel(
    const float* __restrict__ x0, const float* __restrict__ cond,
    const float* __restrict__ times,
    const float* __restrict__ sf_w1, const float* __restrict__ sf_b1,
    const float* __restrict__ sf_w2, const float* __restrict__ sf_b2,
    const float* __restrict__ sf_w3, const float* __restrict__ sf_b3,
    const float* __restrict__ h0wp, const float* __restrict__ h0_b,
    const f16* __restrict__ whf16, const float* __restrict__ gru_bh,
    const float* __restrict__ gru_wi, const float* __restrict__ gru_bi,
    const float* __restrict__ hd_w, const float* __restrict__ hd_b,
    float* __restrict__ pred, float* __restrict__ stopl)
{
    __shared__ __align__(16) f16 hl[2][32 * 128];   // swizzled, row stride 256B
    __shared__ float dl[32 * 66];
    __shared__ __align__(16) float ubuf[4224];      // init-scratch UNION out-stash [32][132]
    __shared__ __align__(16) f16 hds[2 * 128];
    __shared__ float wis[384], bis[384], bhs[384];
    int tid = threadIdx.x;
    int row0 = blockIdx.x * 32;
    int lane = tid & 63, wn = tid >> 6;
    int l15 = lane & 15, l4 = lane >> 4;

    if (tid < 384) { wis[tid] = gru_wi[tid]; bis[tid] = gru_bi[tid]; bhs[tid] = gru_bh[tid]; }
    if (tid < 256) hds[tid] = (f16)hd_w[tid];
    float* tb = ubuf;   // [32][64]
    for (int u = tid; u < 2048; u += 512) {
        int r = u >> 6, k = u & 63;
        tb[u] = times[(size_t)(row0 + r) * TMAXN + k];
    }
    __syncthreads();
    float dtmp[5]; int c = 0;
    for (int idx = tid; idx < 2080; idx += 512) {
        int r = idx / 65, i = idx % 65;
        float v;
        if (i == 0) v = 0.f;
        else if (i == 1) v = tb[r * 64];
        else v = tb[r * 64 + i - 1] - tb[r * 64 + i - 2];
        dtmp[c++] = v;
    }
    __syncthreads();
    c = 0;
    for (int idx = tid; idx < 2080; idx += 512) {
        int r = idx / 65, i = idx % 65;
        dl[r * 66 + i] = dtmp[c++];
    }
    float* in2 = ubuf;            // [32][76]
    float* sbuf = ubuf + 32 * 76; // [32][44]
    for (int idx = tid; idx < 2048; idx += 512) {
        int r = idx >> 6, k = idx & 63;
        in2[r * 76 + k] = cond[(size_t)(row0 + r) * CONDD + k];
    }
    for (int idx = tid; idx < 320; idx += 512) {
        int r = idx / 10, k = idx % 10;
        in2[r * 76 + 64 + k] = x0[(size_t)(row0 + r) * 10 + k];
    }
    if (tid < 64) { int r = tid >> 1; in2[r * 76 + 74 + (tid & 1)] = 0.f; }
    __syncthreads();
    for (int idx = tid; idx < 640; idx += 512) {
        int r = idx / 20, j = idx % 20;
        float a = sf_b1[j];
        for (int k = 0; k < 10; ++k) a += in2[r * 76 + 64 + k] * sf_w1[j * 10 + k];
        sbuf[r * 44 + j] = fmaxf(a, 0.f);
    }
    __syncthreads();
    for (int idx = tid; idx < 640; idx += 512) {
        int r = idx / 20, j = idx % 20;
        float a = sf_b2[j];
        for (int k = 0; k < 20; ++k) a += sbuf[r * 44 + k] * sf_w2[j * 20 + k];
        sbuf[r * 44 + 22 + j] = fmaxf(a, 0.f);
    }
    __syncthreads();
    for (int idx = tid; idx < 320; idx += 512) {
        int r = idx / 10, j = idx % 10;
        float a = sf_b3[j];
        for (int k = 0; k < 20; ++k) a += sbuf[r * 44 + 22 + k] * sf_w3[j * 20 + k];
        in2[r * 76 + 64 + j] = a;
    }
    __syncthreads();
    for (int idx = tid; idx < 4096; idx += 512) {
        int r = idx >> 7, j = idx & 127;
        float a = h0_b[j];
        const f4* wr = (const f4*)(h0wp + j * 76);
        const f4* iv = (const f4*)(in2 + r * 76);
        #pragma unroll
        for (int q = 0; q < 19; ++q) {
            f4 w = wr[q], v = iv[q];
            a += v[0] * w[0] + v[1] * w[1] + v[2] * w[2] + v[3] * w[3];
        }
        *(f16*)((char*)hl[0] + ((r * 256 + j * 2) ^ ((r & 7) << 4))) = (f16)ftanh(a);
    }
    __syncthreads();

    int jc = wn * 16 + l15;
    f16x8 BW[3][4];
    float wi_[3], bi_[3], bh_[3];
    #pragma unroll
    for (int g = 0; g < 3; ++g) {
        int col = g * 128 + jc;
        #pragma unroll
        for (int kb = 0; kb < 4; ++kb)
            BW[g][kb] = *(const f16x8*)(whf16 + col * 128 + kb * 32 + l4 * 8);
        wi_[g] = wis[col]; bi_[g] = bis[col]; bh_[g] = bhs[col];
    }
    float hb0 = hd_b[0], hb1 = hd_b[1];
    float hreg[2][4];
    #pragma unroll
    for (int mr = 0; mr < 2; ++mr)
        #pragma unroll
        for (int r = 0; r < 4; ++r) {
            int row = mr * 16 + l4 * 4 + r;
            hreg[mr][r] = (float)(*(const f16*)((const char*)hl[0] + ((row * 256 + jc * 2) ^ ((row & 7) << 4))));
        }
    float* outb = ubuf;   // [32][132]

    #pragma unroll 1
    for (int s = 0; s < TMAXN + 1; ++s) {
        const f16* cur = hl[s & 1];
        f16* nxt = hl[(s + 1) & 1];
        #pragma unroll
        for (int mr = 0; mr < 2; ++mr) {
            int arow = mr * 16 + l15;
            int aswz = (arow & 7) << 4;
            f16x8 A[4];
            #pragma unroll
            for (int kb = 0; kb < 4; ++kb)
                A[kb] = *(const f16x8*)((const char*)cur + ((arow * 256 + kb * 64 + l4 * 16) ^ aswz));
            if (wn == 0 && s > 0) {
                float pa = 0.f, pb = 0.f;
                #pragma unroll
                for (int kb = 0; kb < 4; ++kb) {
                    f16x8 ha = *(const f16x8*)(hds + kb * 32 + l4 * 8);
                    f16x8 hbv = *(const f16x8*)(hds + 128 + kb * 32 + l4 * 8);
                    #pragma unroll
                    for (int e = 0; e < 8; ++e) {
                        pa += (float)(A[kb][e]) * (float)(ha[e]);
                        pb += (float)(A[kb][e]) * (float)(hbv[e]);
                    }
                }
                pa += __shfl_xor(pa, 16); pa += __shfl_xor(pa, 32);
                pb += __shfl_xor(pb, 16); pb += __shfl_xor(pb, 32);
                if (l4 == 0) {
                    outb[arow * 132 + (s - 1)] = pa + hb0;
                    outb[arow * 132 + 66 + (s - 1)] = pb + hb1;
                }
            }
            f32x4 acc[3];
            #pragma unroll
            for (int g = 0; g < 3; ++g) {
                f32x4 ci; ci[0] = ci[1] = ci[2] = ci[3] = bh_[g];
                acc[g] = ci;
            }
            #pragma unroll
            for (int kb = 0; kb < 4; ++kb)
                #pragma unroll
                for (int g = 0; g < 3; ++g)
                    acc[g] = __builtin_amdgcn_mfma_f32_16x16x32_f16(A[kb], BW[g][kb], acc[g], 0, 0, 0);
            #pragma unroll
            for (int r = 0; r < 4; ++r) {
                int row = mr * 16 + l4 * 4 + r;
                float xv = dl[row * 66 + s];
                float rr = fsig(xv * wi_[0] + bi_[0] + acc[0][r]);
                float zz = fsig(xv * wi_[1] + bi_[1] + acc[1][r]);
                float nn = ftanh(xv * wi_[2] + bi_[2] + rr * acc[2][r]);
                float hn = (1.f - zz) * nn + zz * hreg[mr][r];
                hreg[mr][r] = hn;
                *(f16*)((char*)nxt + ((row * 256 + jc * 2) ^ ((row & 7) << 4))) = (f16)hn;
            }
        }
        __syncthreads();
    }
    if (wn == 0) {
        #pragma unroll
        for (int mr = 0; mr < 2; ++mr) {
            int arow = mr * 16 + l15;
            int aswz = (arow & 7) << 4;
            float pa = 0.f, pb = 0.f;
            #pragma unroll
            for (int kb = 0; kb < 4; ++kb) {
                f16x8 A = *(const f16x8*)((const char*)hl[1] + ((arow * 256 + kb * 64 + l4 * 16) ^ aswz));
                f16x8 ha = *(const f16x8*)(hds + kb * 32 + l4 * 8);
                f16x8 hbv = *(const f16x8*)(hds + 128 + kb * 32 + l4 * 8);
                #pragma unroll
                for (int e = 0; e < 8; ++e) {
                    pa += (float)(A[e]) * (float)(ha[e]);
                    pb += (float)(A[e]) * (float)(hbv[e]);
                }
            }
            pa += __shfl_xor(pa, 16); pa += __shfl_xor(pa, 32);
            pb += __shfl_xor(pb, 16); pb += __shfl_xor(pb, 32);
            if (l4 == 0) {
                outb[arow * 132 + 64] = pa + hb0;
                outb[arow * 132 + 66 + 64] = pb + hb1;
            }
        }
    }
    __syncthreads();
    for (int u = tid; u < 2080; u += 512) {
        int r = u / 65, i = u % 65;
        pred[(size_t)(row0 + r) * (TMAXN + 1) + i] = outb[r * 132 + i];
        stopl[(size_t)(row0 + r) * (TMAXN + 1) + i] = outb[r * 132 + 66 + i];
    }
}

extern "C" void kernel_launch(void* const* d_in, const int* in_sizes, int n_in,
                              void* d_out, int out_size, void* d_ws, size_t ws_size,
                              hipStream_t stream)
{
    const float* bert       = (const float*)d_in[0];
    const float* times      = (const float*)d_in[1];
    const float* init_noise = (const float*)d_in[2];
    const float* step_noise = (const float*)d_in[3];
    const float* bp_w  = (const float*)d_in[4];
    const float* bp_b  = (const float*)d_in[5];
    const float* ln_g  = (const float*)d_in[6];
    const float* ln_b  = (const float*)d_in[7];
    const float* tp_w1 = (const float*)d_in[8];
    const float* tp_b1 = (const float*)d_in[9];
    const float* tp_w2 = (const float*)d_in[10];
    const float* tp_b2 = (const float*)d_in[11];
    const float* dn_w1 = (const float*)d_in[12];
    const float* dn_b1 = (const float*)d_in[13];
    const float* dn_w2 = (const float*)d_in[14];
    const float* dn_b2 = (const float*)d_in[15];
    const float* dn_w3 = (const float*)d_in[16];
    const float* dn_b3 = (const float*)d_in[17];
    const float* sf_w1 = (const float*)d_in[18];
    const float* sf_b1 = (const float*)d_in[19];
    const float* sf_w2 = (const float*)d_in[20];
    const float* sf_b2 = (const float*)d_in[21];
    const float* sf_w3 = (const float*)d_in[22];
    const float* sf_b3 = (const float*)d_in[23];
    const float* h0_w  = (const float*)d_in[24];
    const float* h0_b  = (const float*)d_in[25];
    const float* gru_wi = (const float*)d_in[26];
    const float* gru_bi = (const float*)d_in[27];
    const float* gru_wh = (const float*)d_in[28];
    const float* gru_bh = (const float*)d_in[29];
    const float* hd_w   = (const float*)d_in[30];
    const float* hd_b   = (const float*)d_in[31];

    float* ws    = (float*)d_ws;
    float* cond  = ws;                          // B*64
    float* te    = cond + (size_t)NB * CONDD;   // 50*64
    float* b1eff = te + SAMPLE_TN * TEMBD;      // 50*256
    float* w1ct  = b1eff + SAMPLE_TN * 256;     // 64*256 (fp32, k-major)
    float* h0wp  = w1ct + 64 * 256;             // 128*76
    f16*   w1x16 = (f16*)(h0wp + 128 * 76);     // 256*32 f16
    f16*   w2f16 = w1x16 + 256 * 32;            // 256*256 f16
    f16*   whf16 = w2f16 + 256 * 256;           // 384*128 f16
    f16*   w3f16 = whf16 + 384 * 128;           // 16*256 f16
    f16*   bpw16 = w3f16 + 16 * 256;            // 64*768 f16

    double ab[TDIFFN + 1];
    for (int i = 0; i <= TDIFFN; ++i) {
        double xx = (double)i / (double)TDIFFN;
        double v = cos((xx + 0.008) / 1.008 * M_PI * 0.5);
        ab[i] = v * v;
    }
    double ab0 = ab[0];
    for (int i = 0; i <= TDIFFN; ++i) ab[i] /= ab0;
    double betas[TDIFFN], alphas[TDIFFN], abar[TDIFFN];
    double cp = 1.0;
    for (int i = 0; i < TDIFFN; ++i) {
        double b = 1.0 - ab[i + 1] / ab[i];
        if (b > 0.9999) b = 0.9999;
        betas[i] = b; alphas[i] = 1.0 - b;
        cp *= alphas[i]; abar[i] = cp;
    }
    Sched sc;
    for (int s = 0; s < SAMPLE_TN; ++s) {
        int tt = TDIFFN - 1 - 4 * s;
        double abt = abar[tt];
        double abp = (tt > 0) ? abar[tt - 1] : 1.0;
        double beta = betas[tt];
        sc.c1[s] = (float)(sqrt(abp) * beta / (1.0 - abt));
        sc.c2[s] = (float)(sqrt(alphas[tt]) * (1.0 - abp) / (1.0 - abt));
        sc.sv[s] = (float)((tt > 0) ? sqrt((1.0 - abp) / (1.0 - abt) * beta) : 0.0);
        sc.ts[s] = (float)tt;
    }

    float* out    = (float*)d_out;
    float* out_x0 = out;
    float* pred   = out + (size_t)NB * INUMD;
    float* stopl  = pred + (size_t)NB * (TMAXN + 1);

    pack_kernel<<<256, 256, 0, stream>>>(dn_w1, dn_w2, dn_w3, gru_wh, h0_w, bp_w,
                                         w1ct, w1x16, w2f16, whf16, h0wp, bpw16, w3f16);
    bert2_kernel<<<NB / 64, 256, 0, stream>>>(bert, bpw16, bp_b, ln_g, ln_b, cond);
    te_kernel<<<SAMPLE_TN, 128, 0, stream>>>(tp_w1, tp_b1, tp_w2, tp_b2, te, sc);
    b1eff_kernel<<<SAMPLE_TN, 256, 0, stream>>>(te, dn_w1, dn_b1, b1eff);

    ddpm_all_kernel<<<NB / 32, 256, 0, stream>>>(
        init_noise, cond, step_noise, w1ct, w1x16, b1eff, w2f16, dn_b2, w3f16, dn_b3,
        sc, out_x0);

    gru_all_kernel<<<NB / 32, 512, 0, stream>>>(
        out_x0, cond, times,
        sf_w1, sf_b1, sf_w2, sf_b2, sf_w3, sf_b3,
        h0wp, h0_b, whf16, gru_bh, gru_wi, gru_bi, hd_w, hd_b,
        pred, stopl);
}

// Round 12
// 520.653 us; speedup vs baseline: 2.0715x; 2.0715x over previous
//
#include <hip/hip_runtime.h>
#include <math.h>

typedef float f4 __attribute__((ext_vector_type(4)));
typedef float f32x4 __attribute__((ext_vector_type(4)));
typedef _Float16 f16;
typedef _Float16 f16x8 __attribute__((ext_vector_type(8)));

#define NB 16384
#define BERT_DIM 768
#define CONDD 64
#define INUMD 10
#define RNND 128
#define TDIFFN 200
#define SAMPLE_TN 50
#define TEMBD 64
#define TMAXN 64

struct Sched { float c1[SAMPLE_TN], c2[SAMPLE_TN], sv[SAMPLE_TN], ts[SAMPLE_TN]; };

__device__ __forceinline__ float fsig(float v)  { return __builtin_amdgcn_rcpf(1.f + __expf(-v)); }
__device__ __forceinline__ float ftanh(float v) { return 1.f - 2.f * __builtin_amdgcn_rcpf(1.f + __expf(2.f * v)); }
__device__ __forceinline__ float fsilu(float v) { return v * fsig(v); }

// ---------------- pack: transposed / fp16 weights ----------------
__global__ __launch_bounds__(256) void pack_kernel(
    const float* __restrict__ dn_w1, const float* __restrict__ dn_w2,
    const float* __restrict__ dn_w3, const float* __restrict__ gru_wh,
    const float* __restrict__ h0_w, const float* __restrict__ bp_w,
    float* __restrict__ w1ct, f16* __restrict__ w1x16, f16* __restrict__ w2f16,
    f16* __restrict__ whf16, float* __restrict__ h0wp, f16* __restrict__ bpw16,
    f16* __restrict__ w3f16)
{
    int idx = blockIdx.x * 256 + threadIdx.x;   // 0..65535
    if (idx < 16384) { int k = idx >> 8, n = idx & 255; w1ct[idx] = dn_w1[n * 138 + 10 + k]; }
    if (idx < 8192)  { int n = idx >> 5, k = idx & 31; w1x16[idx] = (f16)(k < 10 ? dn_w1[n * 138 + k] : 0.f); }
    if (idx < 65536) { w2f16[idx] = (f16)dn_w2[idx]; }                 // [n=256][k=256]
    if (idx < 49152) { whf16[idx] = (f16)gru_wh[idx]; }                // [n=384][k=128]
    if (idx < 9728)  { int r = idx / 76, c = idx % 76; h0wp[idx] = (c < 74) ? h0_w[r * 74 + c] : 0.f; }
    if (idx < 49152) { bpw16[idx] = (f16)bp_w[idx]; }                  // [n=64][k=768]
    if (idx < 4096)  { int n = idx >> 8, k = idx & 255; w3f16[idx] = (f16)(n < 10 ? dn_w3[n * 256 + k] : 0.f); }
}

// ---------------- bert proj + LN, fp16 MFMA (r11-proven): 64 rows/block, W staged in LDS ----------------
__global__ __launch_bounds__(256, 1) void bert2_kernel(
    const float* __restrict__ bert, const f16* __restrict__ bpw16,
    const float* __restrict__ bp_b, const float* __restrict__ ln_g,
    const float* __restrict__ ln_b, float* __restrict__ cond)
{
    __shared__ __align__(16) f16 ws16[64 * 768];   // 96 KB, swizzled: n*1536B + (k*2 ^ ((n&7)<<4))
    int tid = threadIdx.x;
    int row0 = blockIdx.x * 64;
    int lane = tid & 63, wn = tid >> 6;
    int l15 = lane & 15, l4 = lane >> 4;

    for (int u = tid; u < 6144; u += 256) {
        int n = u / 96, k8 = u % 96;
        *(f16x8*)((char*)ws16 + n * 1536 + ((k8 * 16) ^ ((n & 7) << 4))) =
            *(const f16x8*)(bpw16 + n * 768 + k8 * 8);
    }
    __syncthreads();

    const float* aptr = bert + (size_t)(row0 + wn * 16 + l15) * BERT_DIM;
    f32x4 acc[4];
    #pragma unroll
    for (int t = 0; t < 4; ++t) {
        float bb = bp_b[t * 16 + l15];
        acc[t][0] = bb; acc[t][1] = bb; acc[t][2] = bb; acc[t][3] = bb;
    }
    #pragma unroll 4
    for (int kb = 0; kb < 24; ++kb) {
        f4 a0 = *(const f4*)(aptr + kb * 32 + l4 * 8);
        f4 a1 = *(const f4*)(aptr + kb * 32 + l4 * 8 + 4);
        f16x8 af;
        #pragma unroll
        for (int j = 0; j < 4; ++j) { af[j] = (f16)a0[j]; af[4 + j] = (f16)a1[j]; }
        #pragma unroll
        for (int t = 0; t < 4; ++t) {
            int col = t * 16 + l15;
            f16x8 bf = *(const f16x8*)((const char*)ws16 +
                        (col * 1536 + ((kb * 64 + l4 * 16) ^ ((col & 7) << 4))));
            acc[t] = __builtin_amdgcn_mfma_f32_16x16x32_f16(af, bf, acc[t], 0, 0, 0);
        }
    }
    float s[4] = {0,0,0,0}, s2[4] = {0,0,0,0};
    #pragma unroll
    for (int r = 0; r < 4; ++r)
        #pragma unroll
        for (int t = 0; t < 4; ++t) { float v = acc[t][r]; s[r] += v; s2[r] += v * v; }
    #pragma unroll
    for (int r = 0; r < 4; ++r) {
        #pragma unroll
        for (int off = 1; off < 16; off <<= 1) {
            s[r] += __shfl_xor(s[r], off);
            s2[r] += __shfl_xor(s2[r], off);
        }
    }
    float mu[4], inv[4];
    #pragma unroll
    for (int r = 0; r < 4; ++r) {
        mu[r] = s[r] * (1.f / 64.f);
        float var = s2[r] * (1.f / 64.f) - mu[r] * mu[r];
        inv[r] = rsqrtf(var + 1e-5f);
    }
    #pragma unroll
    for (int t = 0; t < 4; ++t) {
        int col = t * 16 + l15;
        float g = ln_g[col], b = ln_b[col];
        #pragma unroll
        for (int r = 0; r < 4; ++r) {
            int row = row0 + wn * 16 + l4 * 4 + r;
            cond[(size_t)row * CONDD + col] = (acc[t][r] - mu[r]) * inv[r] * g + b;
        }
    }
}

// ---------------- time embedding MLP ----------------
__global__ __launch_bounds__(128) void te_kernel(
    const float* __restrict__ tp_w1, const float* __restrict__ tp_b1,
    const float* __restrict__ tp_w2, const float* __restrict__ tp_b2,
    float* __restrict__ te, Sched sc)
{
    __shared__ float temb[TEMBD];
    __shared__ float h[TEMBD * 2];
    int s = blockIdx.x, t = threadIdx.x;
    if (t < 32) {
        float freq = expf(-logf(10000.f) * (float)t / 31.f);
        float e = sc.ts[s] * freq;
        temb[t] = sinf(e);
        temb[t + 32] = cosf(e);
    }
    __syncthreads();
    float a = tp_b1[t];
    for (int k = 0; k < TEMBD; ++k) a += temb[k] * tp_w1[t * TEMBD + k];
    h[t] = a * (1.f / (1.f + expf(-a)));
    __syncthreads();
    if (t < TEMBD) {
        float a2 = tp_b2[t];
        for (int k = 0; k < 128; ++k) a2 += h[k] * tp_w2[t * 128 + k];
        te[s * TEMBD + t] = a2;
    }
}

// ---------------- b1eff[s][n] = b1[n] + sum_k te[s][k]*w1[n][74+k] ----------------
__global__ __launch_bounds__(256) void b1eff_kernel(
    const float* __restrict__ te, const float* __restrict__ dn_w1,
    const float* __restrict__ dn_b1, float* __restrict__ b1eff)
{
    __shared__ float tes[64];
    int s = blockIdx.x, n = threadIdx.x;
    if (n < 64) tes[n] = te[s * 64 + n];
    __syncthreads();
    float a = dn_b1[n];
    for (int k = 0; k < 64; ++k) a += tes[k] * dn_w1[n * 138 + 74 + k];
    b1eff[s * 256 + n] = a;
}

// ---------------- DDPM (r5/r10-proven, 343us): 16 rows/block, 4 waves x 64 cols, 2 barriers/step.
// cond1 in registers (MFMA-C layout); B1/B2/W3 weight-stationary; per-wave x buffer, no 3rd barrier.
__global__ __launch_bounds__(256, 2) void ddpm_all_kernel(
    const float* __restrict__ x_init, const float* __restrict__ cond,
    const float* __restrict__ noise,
    const float* __restrict__ w1ct, const f16* __restrict__ w1x16,
    const float* __restrict__ b1eff, const f16* __restrict__ w2f16,
    const float* __restrict__ b2g, const f16* __restrict__ w3f16,
    const float* __restrict__ b3g, Sched sc, float* __restrict__ out_x0)
{
    __shared__ __align__(16) f16 h1[16 * 256];      // swizzled, row stride 512B
    __shared__ __align__(16) f16 h2[16 * 256];      // swizzled, row stride 512B
    __shared__ __align__(16) f16 xw[4][16 * 32];    // per-wave x, linear, row stride 64B
    int tid = threadIdx.x;
    int row0 = blockIdx.x * 16;
    int lane = tid & 63, wn = tid >> 6;
    int l15 = lane & 15, l4 = lane >> 4;

    // stage cond fp32 into h1-scratch; zero own-wave x buffer
    float* condl = (float*)h1;   // [16][64]
    {
        int r = tid >> 4, q = tid & 15;
        *(f4*)(condl + r * 64 + q * 4) = *(const f4*)(cond + (size_t)(row0 + r) * 64 + q * 4);
    }
    *(f4*)((float*)&xw[wn][0] + lane * 4) = (f4)0.f;     // 64 lanes x 16B = 1KB
    __syncthreads();

    // cond1 in regs: c1r[t][r] = sum_k cond[row=l4*4+r][k] * w1c[col][k]
    f32x4 c1r[4];
    #pragma unroll
    for (int t = 0; t < 4; ++t) c1r[t] = (f32x4)0.f;
    for (int kq = 0; kq < 16; ++kq) {
        f4 cr[4];
        #pragma unroll
        for (int r = 0; r < 4; ++r) cr[r] = *(const f4*)(condl + (l4 * 4 + r) * 64 + kq * 4);
        #pragma unroll
        for (int t = 0; t < 4; ++t) {
            int col = wn * 64 + t * 16 + l15;
            #pragma unroll
            for (int j = 0; j < 4; ++j) {
                float w = w1ct[(kq * 4 + j) * 256 + col];
                #pragma unroll
                for (int r = 0; r < 4; ++r) c1r[t][r] += cr[r][j] * w;
            }
        }
    }
    __syncthreads();   // condl scratch done; h1 free for reuse

    // preload weights into registers
    f16x8 B2[4][8], B1[4], W3[8];
    float b2v[4];
    #pragma unroll
    for (int t = 0; t < 4; ++t) {
        int col = wn * 64 + t * 16 + l15;
        B1[t] = *(const f16x8*)(w1x16 + col * 32 + l4 * 8);
        #pragma unroll
        for (int kb = 0; kb < 8; ++kb)
            B2[t][kb] = *(const f16x8*)(w2f16 + col * 256 + kb * 32 + l4 * 8);
        b2v[t] = b2g[col];
    }
    #pragma unroll
    for (int kb = 0; kb < 8; ++kb)
        W3[kb] = *(const f16x8*)(w3f16 + l15 * 256 + kb * 32 + l4 * 8);
    float b3v = (l15 < 10) ? b3g[l15] : 0.f;

    // x state in regs (rows l4*4+r, k=l15) + own-wave fp16 copy
    float xo[4] = {0.f, 0.f, 0.f, 0.f};
    if (l15 < 10) {
        #pragma unroll
        for (int r = 0; r < 4; ++r) {
            xo[r] = x_init[(size_t)(row0 + l4 * 4 + r) * INUMD + l15];
            xw[wn][(l4 * 4 + r) * 32 + l15] = (f16)xo[r];
        }
    }
    float be[4];
    #pragma unroll
    for (int t = 0; t < 4; ++t) be[t] = b1eff[wn * 64 + t * 16 + l15];

    int axoff = l15 * 64 + l4 * 16;   // bytes in xw[wn]
    #pragma unroll 1
    for (int s = 0; s < SAMPLE_TN; ++s) {
        // ---- L1: h1 = silu(x @ w1x^T + cond1 + b1eff[s]) ----
        f16x8 ax = *(const f16x8*)((const char*)xw[wn] + axoff);
        #pragma unroll
        for (int t = 0; t < 4; ++t) {
            f32x4 ci;
            #pragma unroll
            for (int r = 0; r < 4; ++r) ci[r] = c1r[t][r] + be[t];
            f32x4 a1 = __builtin_amdgcn_mfma_f32_16x16x32_f16(ax, B1[t], ci, 0, 0, 0);
            int col = wn * 64 + t * 16 + l15;
            #pragma unroll
            for (int r = 0; r < 4; ++r) {
                int row = l4 * 4 + r;
                *(f16*)((char*)h1 + ((row * 512 + col * 2) ^ ((row & 7) << 4))) = (f16)fsilu(a1[r]);
            }
        }
        // prefetch noise (used in L3) and next-step b1eff
        float nz[4] = {0.f, 0.f, 0.f, 0.f};
        if (l15 < 10) {
            #pragma unroll
            for (int r = 0; r < 4; ++r)
                nz[r] = noise[((size_t)s * NB + row0 + l4 * 4 + r) * INUMD + l15];
        }
        if (s + 1 < SAMPLE_TN) {
            #pragma unroll
            for (int t = 0; t < 4; ++t) be[t] = b1eff[(s + 1) * 256 + wn * 64 + t * 16 + l15];
        }
        __syncthreads();
        // ---- L2: h2 = silu(h1 @ w2^T + b2) ----
        {
            f32x4 a2[4];
            #pragma unroll
            for (int t = 0; t < 4; ++t) a2[t] = (f32x4)0.f;
            #pragma unroll
            for (int kb = 0; kb < 8; ++kb) {
                f16x8 A = *(const f16x8*)((const char*)h1 +
                          (l15 * 512 + ((kb * 64 + l4 * 16) ^ ((l15 & 7) << 4))));
                #pragma unroll
                for (int t = 0; t < 4; ++t)
                    a2[t] = __builtin_amdgcn_mfma_f32_16x16x32_f16(A, B2[t][kb], a2[t], 0, 0, 0);
            }
            #pragma unroll
            for (int t = 0; t < 4; ++t) {
                int col = wn * 64 + t * 16 + l15;
                #pragma unroll
                for (int r = 0; r < 4; ++r) {
                    int row = l4 * 4 + r;
                    *(f16*)((char*)h2 + ((row * 512 + col * 2) ^ ((row & 7) << 4))) = (f16)fsilu(a2[t][r] + b2v[t]);
                }
            }
        }
        __syncthreads();
        // ---- L3: p = h2 @ w3^T (N=16 padded), then ancestral update in-lane ----
        {
            f32x4 pa = (f32x4)0.f, pb = (f32x4)0.f;
            #pragma unroll
            for (int kb = 0; kb < 8; kb += 2) {
                f16x8 A0 = *(const f16x8*)((const char*)h2 +
                           (l15 * 512 + (((kb + 0) * 64 + l4 * 16) ^ ((l15 & 7) << 4))));
                f16x8 A1 = *(const f16x8*)((const char*)h2 +
                           (l15 * 512 + (((kb + 1) * 64 + l4 * 16) ^ ((l15 & 7) << 4))));
                pa = __builtin_amdgcn_mfma_f32_16x16x32_f16(A0, W3[kb + 0], pa, 0, 0, 0);
                pb = __builtin_amdgcn_mfma_f32_16x16x32_f16(A1, W3[kb + 1], pb, 0, 0, 0);
            }
            if (l15 < 10) {
                float c1s = sc.c1[s], c2s = sc.c2[s], svs = sc.sv[s];
                #pragma unroll
                for (int r = 0; r < 4; ++r) {
                    float xn = c1s * (pa[r] + pb[r] + b3v) + c2s * xo[r] + svs * nz[r];
                    xo[r] = xn;
                    xw[wn][(l4 * 4 + r) * 32 + l15] = (f16)xn;
                }
            }
        }
        // no barrier: xw is per-wave (lgkmcnt covers own write->read);
        // h1 writes next iter are safe (everyone passed bar2 of this step)
    }
    if (wn == 0 && l15 < 10) {
        #pragma unroll
        for (int r = 0; r < 4; ++r)
            out_x0[(size_t)(row0 + l4 * 4 + r) * INUMD + l15] = xo[r];
    }
}

// ---------------- GRU v3 (r7/r9/r10-proven): 8 waves x 16 cols, head via dot on A-frags ----------------
__global__ __launch_bounds__(512, 4) void gru_all_kernel(
    const float* __restrict__ x0, const float* __restrict__ cond,
    const float* __restrict__ times,
    const float* __restrict__ sf_w1, const float* __restrict__ sf_b1,
    const float* __restrict__ sf_w2, const float* __restrict__ sf_b2,
    const float* __restrict__ sf_w3, const float* __restrict__ sf_b3,
    const float* __restrict__ h0wp, const float* __restrict__ h0_b,
    const f16* __restrict__ whf16, const float* __restrict__ gru_bh,
    const float* __restrict__ gru_wi, const float* __restrict__ gru_bi,
    const float* __restrict__ hd_w, const float* __restrict__ hd_b,
    float* __restrict__ pred, float* __restrict__ stopl)
{
    __shared__ __align__(16) f16 hl[2][32 * 128];   // swizzled, row stride 256B
    __shared__ float dl[32 * 66];
    __shared__ __align__(16) float ubuf[4224];      // init-scratch UNION out-stash [32][132]
    __shared__ __align__(16) f16 hds[2 * 128];
    __shared__ float wis[384], bis[384], bhs[384];
    int tid = threadIdx.x;
    int row0 = blockIdx.x * 32;
    int lane = tid & 63, wn = tid >> 6;
    int l15 = lane & 15, l4 = lane >> 4;

    if (tid < 384) { wis[tid] = gru_wi[tid]; bis[tid] = gru_bi[tid]; bhs[tid] = gru_bh[tid]; }
    if (tid < 256) hds[tid] = (f16)hd_w[tid];
    float* tb = ubuf;   // [32][64]
    for (int u = tid; u < 2048; u += 512) {
        int r = u >> 6, k = u & 63;
        tb[u] = times[(size_t)(row0 + r) * TMAXN + k];
    }
    __syncthreads();
    float dtmp[5]; int c = 0;
    for (int idx = tid; idx < 2080; idx += 512) {
        int r = idx / 65, i = idx % 65;
        float v;
        if (i == 0) v = 0.f;
        else if (i == 1) v = tb[r * 64];
        else v = tb[r * 64 + i - 1] - tb[r * 64 + i - 2];
        dtmp[c++] = v;
    }
    __syncthreads();
    c = 0;
    for (int idx = tid; idx < 2080; idx += 512) {
        int r = idx / 65, i = idx % 65;
        dl[r * 66 + i] = dtmp[c++];
    }
    float* in2 = ubuf;            // [32][76]
    float* sbuf = ubuf + 32 * 76; // [32][44]
    for (int idx = tid; idx < 2048; idx += 512) {
        int r = idx >> 6, k = idx & 63;
        in2[r * 76 + k] = cond[(size_t)(row0 + r) * CONDD + k];
    }
    for (int idx = tid; idx < 320; idx += 512) {
        int r = idx / 10, k = idx % 10;
        in2[r * 76 + 64 + k] = x0[(size_t)(row0 + r) * 10 + k];
    }
    if (tid < 64) { int r = tid >> 1; in2[r * 76 + 74 + (tid & 1)] = 0.f; }
    __syncthreads();
    for (int idx = tid; idx < 640; idx += 512) {
        int r = idx / 20, j = idx % 20;
        float a = sf_b1[j];
        for (int k = 0; k < 10; ++k) a += in2[r * 76 + 64 + k] * sf_w1[j * 10 + k];
        sbuf[r * 44 + j] = fmaxf(a, 0.f);
    }
    __syncthreads();
    for (int idx = tid; idx < 640; idx += 512) {
        int r = idx / 20, j = idx % 20;
        float a = sf_b2[j];
        for (int k = 0; k < 20; ++k) a += sbuf[r * 44 + k] * sf_w2[j * 20 + k];
        sbuf[r * 44 + 22 + j] = fmaxf(a, 0.f);
    }
    __syncthreads();
    for (int idx = tid; idx < 320; idx += 512) {
        int r = idx / 10, j = idx % 10;
        float a = sf_b3[j];
        for (int k = 0; k < 20; ++k) a += sbuf[r * 44 + 22 + k] * sf_w3[j * 20 + k];
        in2[r * 76 + 64 + j] = a;
    }
    __syncthreads();
    for (int idx = tid; idx < 4096; idx += 512) {
        int r = idx >> 7, j = idx & 127;
        float a = h0_b[j];
        const f4* wr = (const f4*)(h0wp + j * 76);
        const f4* iv = (const f4*)(in2 + r * 76);
        #pragma unroll
        for (int q = 0; q < 19; ++q) {
            f4 w = wr[q], v = iv[q];
            a += v[0] * w[0] + v[1] * w[1] + v[2] * w[2] + v[3] * w[3];
        }
        *(f16*)((char*)hl[0] + ((r * 256 + j * 2) ^ ((r & 7) << 4))) = (f16)ftanh(a);
    }
    __syncthreads();

    int jc = wn * 16 + l15;
    f16x8 BW[3][4];
    float wi_[3], bi_[3], bh_[3];
    #pragma unroll
    for (int g = 0; g < 3; ++g) {
        int col = g * 128 + jc;
        #pragma unroll
        for (int kb = 0; kb < 4; ++kb)
            BW[g][kb] = *(const f16x8*)(whf16 + col * 128 + kb * 32 + l4 * 8);
        wi_[g] = wis[col]; bi_[g] = bis[col]; bh_[g] = bhs[col];
    }
    float hb0 = hd_b[0], hb1 = hd_b[1];
    float hreg[2][4];
    #pragma unroll
    for (int mr = 0; mr < 2; ++mr)
        #pragma unroll
        for (int r = 0; r < 4; ++r) {
            int row = mr * 16 + l4 * 4 + r;
            hreg[mr][r] = (float)(*(const f16*)((const char*)hl[0] + ((row * 256 + jc * 2) ^ ((row & 7) << 4))));
        }
    float* outb = ubuf;   // [32][132]

    #pragma unroll 1
    for (int s = 0; s < TMAXN + 1; ++s) {
        const f16* cur = hl[s & 1];
        f16* nxt = hl[(s + 1) & 1];
        #pragma unroll
        for (int mr = 0; mr < 2; ++mr) {
            int arow = mr * 16 + l15;
            int aswz = (arow & 7) << 4;
            f16x8 A[4];
            #pragma unroll
            for (int kb = 0; kb < 4; ++kb)
                A[kb] = *(const f16x8*)((const char*)cur + ((arow * 256 + kb * 64 + l4 * 16) ^ aswz));
            if (wn == 0 && s > 0) {
                float pa = 0.f, pb = 0.f;
                #pragma unroll
                for (int kb = 0; kb < 4; ++kb) {
                    f16x8 ha = *(const f16x8*)(hds + kb * 32 + l4 * 8);
                    f16x8 hbv = *(const f16x8*)(hds + 128 + kb * 32 + l4 * 8);
                    #pragma unroll
                    for (int e = 0; e < 8; ++e) {
                        pa += (float)(A[kb][e]) * (float)(ha[e]);
                        pb += (float)(A[kb][e]) * (float)(hbv[e]);
                    }
                }
                pa += __shfl_xor(pa, 16); pa += __shfl_xor(pa, 32);
                pb += __shfl_xor(pb, 16); pb += __shfl_xor(pb, 32);
                if (l4 == 0) {
                    outb[arow * 132 + (s - 1)] = pa + hb0;
                    outb[arow * 132 + 66 + (s - 1)] = pb + hb1;
                }
            }
            f32x4 acc[3];
            #pragma unroll
            for (int g = 0; g < 3; ++g) {
                f32x4 ci; ci[0] = ci[1] = ci[2] = ci[3] = bh_[g];
                acc[g] = ci;
            }
            #pragma unroll
            for (int kb = 0; kb < 4; ++kb)
                #pragma unroll
                for (int g = 0; g < 3; ++g)
                    acc[g] = __builtin_amdgcn_mfma_f32_16x16x32_f16(A[kb], BW[g][kb], acc[g], 0, 0, 0);
            #pragma unroll
            for (int r = 0; r < 4; ++r) {
                int row = mr * 16 + l4 * 4 + r;
                float xv = dl[row * 66 + s];
                float rr = fsig(xv * wi_[0] + bi_[0] + acc[0][r]);
                float zz = fsig(xv * wi_[1] + bi_[1] + acc[1][r]);
                float nn = ftanh(xv * wi_[2] + bi_[2] + rr * acc[2][r]);
                float hn = (1.f - zz) * nn + zz * hreg[mr][r];
                hreg[mr][r] = hn;
                *(f16*)((char*)nxt + ((row * 256 + jc * 2) ^ ((row & 7) << 4))) = (f16)hn;
            }
        }
        __syncthreads();
    }
    if (wn == 0) {
        #pragma unroll
        for (int mr = 0; mr < 2; ++mr) {
            int arow = mr * 16 + l15;
            int aswz = (arow & 7) << 4;
            float pa = 0.f, pb = 0.f;
            #pragma unroll
            for (int kb = 0; kb < 4; ++kb) {
                f16x8 A = *(const f16x8*)((const char*)hl[1] + ((arow * 256 + kb * 64 + l4 * 16) ^ aswz));
                f16x8 ha = *(const f16x8*)(hds + kb * 32 + l4 * 8);
                f16x8 hbv = *(const f16x8*)(hds + 128 + kb * 32 + l4 * 8);
                #pragma unroll
                for (int e = 0; e < 8; ++e) {
                    pa += (float)(A[e]) * (float)(ha[e]);
                    pb += (float)(A[e]) * (float)(hbv[e]);
                }
            }
            pa += __shfl_xor(pa, 16); pa += __shfl_xor(pa, 32);
            pb += __shfl_xor(pb, 16); pb += __shfl_xor(pb, 32);
            if (l4 == 0) {
                outb[arow * 132 + 64] = pa + hb0;
                outb[arow * 132 + 66 + 64] = pb + hb1;
            }
        }
    }
    __syncthreads();
    for (int u = tid; u < 2080; u += 512) {
        int r = u / 65, i = u % 65;
        pred[(size_t)(row0 + r) * (TMAXN + 1) + i] = outb[r * 132 + i];
        stopl[(size_t)(row0 + r) * (TMAXN + 1) + i] = outb[r * 132 + 66 + i];
    }
}

extern "C" void kernel_launch(void* const* d_in, const int* in_sizes, int n_in,
                              void* d_out, int out_size, void* d_ws, size_t ws_size,
                              hipStream_t stream)
{
    const float* bert       = (const float*)d_in[0];
    const float* times      = (const float*)d_in[1];
    const float* init_noise = (const float*)d_in[2];
    const float* step_noise = (const float*)d_in[3];
    const float* bp_w  = (const float*)d_in[4];
    const float* bp_b  = (const float*)d_in[5];
    const float* ln_g  = (const float*)d_in[6];
    const float* ln_b  = (const float*)d_in[7];
    const float* tp_w1 = (const float*)d_in[8];
    const float* tp_b1 = (const float*)d_in[9];
    const float* tp_w2 = (const float*)d_in[10];
    const float* tp_b2 = (const float*)d_in[11];
    const float* dn_w1 = (const float*)d_in[12];
    const float* dn_b1 = (const float*)d_in[13];
    const float* dn_w2 = (const float*)d_in[14];
    const float* dn_b2 = (const float*)d_in[15];
    const float* dn_w3 = (const float*)d_in[16];
    const float* dn_b3 = (const float*)d_in[17];
    const float* sf_w1 = (const float*)d_in[18];
    const float* sf_b1 = (const float*)d_in[19];
    const float* sf_w2 = (const float*)d_in[20];
    const float* sf_b2 = (const float*)d_in[21];
    const float* sf_w3 = (const float*)d_in[22];
    const float* sf_b3 = (const float*)d_in[23];
    const float* h0_w  = (const float*)d_in[24];
    const float* h0_b  = (const float*)d_in[25];
    const float* gru_wi = (const float*)d_in[26];
    const float* gru_bi = (const float*)d_in[27];
    const float* gru_wh = (const float*)d_in[28];
    const float* gru_bh = (const float*)d_in[29];
    const float* hd_w   = (const float*)d_in[30];
    const float* hd_b   = (const float*)d_in[31];

    float* ws    = (float*)d_ws;
    float* cond  = ws;                          // B*64
    float* te    = cond + (size_t)NB * CONDD;   // 50*64
    float* b1eff = te + SAMPLE_TN * TEMBD;      // 50*256
    float* w1ct  = b1eff + SAMPLE_TN * 256;     // 64*256 (fp32, k-major)
    float* h0wp  = w1ct + 64 * 256;             // 128*76
    f16*   w1x16 = (f16*)(h0wp + 128 * 76);     // 256*32 f16
    f16*   w2f16 = w1x16 + 256 * 32;            // 256*256 f16
    f16*   whf16 = w2f16 + 256 * 256;           // 384*128 f16
    f16*   w3f16 = whf16 + 384 * 128;           // 16*256 f16
    f16*   bpw16 = w3f16 + 16 * 256;            // 64*768 f16

    double ab[TDIFFN + 1];
    for (int i = 0; i <= TDIFFN; ++i) {
        double xx = (double)i / (double)TDIFFN;
        double v = cos((xx + 0.008) / 1.008 * M_PI * 0.5);
        ab[i] = v * v;
    }
    double ab0 = ab[0];
    for (int i = 0; i <= TDIFFN; ++i) ab[i] /= ab0;
    double betas[TDIFFN], alphas[TDIFFN], abar[TDIFFN];
    double cp = 1.0;
    for (int i = 0; i < TDIFFN; ++i) {
        double b = 1.0 - ab[i + 1] / ab[i];
        if (b > 0.9999) b = 0.9999;
        betas[i] = b; alphas[i] = 1.0 - b;
        cp *= alphas[i]; abar[i] = cp;
    }
    Sched sc;
    for (int s = 0; s < SAMPLE_TN; ++s) {
        int tt = TDIFFN - 1 - 4 * s;
        double abt = abar[tt];
        double abp = (tt > 0) ? abar[tt - 1] : 1.0;
        double beta = betas[tt];
        sc.c1[s] = (float)(sqrt(abp) * beta / (1.0 - abt));
        sc.c2[s] = (float)(sqrt(alphas[tt]) * (1.0 - abp) / (1.0 - abt));
        sc.sv[s] = (float)((tt > 0) ? sqrt((1.0 - abp) / (1.0 - abt) * beta) : 0.0);
        sc.ts[s] = (float)tt;
    }

    float* out    = (float*)d_out;
    float* out_x0 = out;
    float* pred   = out + (size_t)NB * INUMD;
    float* stopl  = pred + (size_t)NB * (TMAXN + 1);

    pack_kernel<<<256, 256, 0, stream>>>(dn_w1, dn_w2, dn_w3, gru_wh, h0_w, bp_w,
                                         w1ct, w1x16, w2f16, whf16, h0wp, bpw16, w3f16);
    bert2_kernel<<<NB / 64, 256, 0, stream>>>(bert, bpw16, bp_b, ln_g, ln_b, cond);
    te_kernel<<<SAMPLE_TN, 128, 0, stream>>>(tp_w1, tp_b1, tp_w2, tp_b2, te, sc);
    b1eff_kernel<<<SAMPLE_TN, 256, 0, stream>>>(te, dn_w1, dn_b1, b1eff);

    ddpm_all_kernel<<<NB / 16, 256, 0, stream>>>(
        init_noise, cond, step_noise, w1ct, w1x16, b1eff, w2f16, dn_b2, w3f16, dn_b3,
        sc, out_x0);

    gru_all_kernel<<<NB / 32, 512, 0, stream>>>(
        out_x0, cond, times,
        sf_w1, sf_b1, sf_w2, sf_b2, sf_w3, sf_b3,
        h0wp, h0_b, whf16, gru_bh, gru_wi, gru_bi, hd_w, hd_b,
        pred, stopl);
}